// Round 3
// baseline (794.844 us; speedup 1.0000x reference)
//
#include <hip/hip_runtime.h>
#include <math.h>

namespace {
constexpr int B_ = 4, K_ = 8, H_ = 512, W_ = 1024;
constexpr int N_ = H_ * W_;            // 524288 pixels per image
constexpr int M_ = 1024;               // err histogram bins over [0,2]
constexpr int BK_ = B_ * K_;
constexpr int KM_ = K_ * M_;           // 8192 bins per block (32 KB LDS)

constexpr int HB_ = 512;               // hist blocks
constexpr int HBPB_ = HB_ / B_;        // 128 blocks per image
constexpr int HCHUNK_ = B_ * N_ / HB_; // 4096 pixels per block
constexpr int SB_ = 1024;              // stats blocks
constexpr int SBPB_ = SB_ / B_;        // 256 per image
constexpr int SCHUNK_ = B_ * N_ / SB_; // 2048 pixels per block

constexpr size_t PART_BYTES = (size_t)HB_ * KM_ * 4;  // 16 MB partial hists

// float region offsets (after partials)
constexpr int CNT_OFF = 0, SX_OFF = BK_, SY_OFF = 2 * BK_, SS_OFF = 3 * BK_, SS2_OFF = 4 * BK_;
constexpr int BG_OFF = 5 * BK_;
constexpr int SEEDFG_OFF = BG_OFF + B_;
constexpr int LOV_OFF = SEEDFG_OFF + BK_;
constexpr int FIN_OFF = LOV_OFF + BK_;     // 5 per (b,k): cx,cy,sexp,counts,var
constexpr int FLOATS_TOTAL = FIN_OFF + 5 * BK_;
}

__device__ __forceinline__ float fsigmoid_(float x) { return 1.0f / (1.0f + __expf(-x)); }
__device__ __forceinline__ float ftanh_(float x) { return 1.0f - 2.0f / (__expf(2.0f * x) + 1.0f); }

// ---------------- Stage 1: per-instance stats + bg seed loss ----------------
__global__ __launch_bounds__(256, 4) void stats_kernel(const float* __restrict__ pred,
                                                       const int* __restrict__ inst,
                                                       const int* __restrict__ lab,
                                                       float* __restrict__ wsf) {
    int tid = threadIdx.x;
    int b = blockIdx.x / SBPB_;
    int pix0 = (blockIdx.x % SBPB_) * SCHUNK_;

    const float* sigp = pred + ((long long)b * 4 + 2) * N_;
    const float* p3p  = pred + ((long long)b * 4 + 3) * N_;
    const int*   insp = inst + (long long)b * N_;
    const int*   labp = lab  + (long long)b * N_;

    float acc[41];
#pragma unroll
    for (int i = 0; i < 41; i++) acc[i] = 0.0f;

#pragma unroll
    for (int it = 0; it < SCHUNK_ / (256 * 4); it++) {   // 2 float4 iterations
        int base = pix0 + (it * 256 + tid) * 4;
        float4 sg = *(const float4*)(sigp + base);
        float4 q3 = *(const float4*)(p3p + base);
        int4 in4 = *(const int4*)(insp + base);
        int4 lb4 = *(const int4*)(labp + base);
        float ss[4] = {sg.x, sg.y, sg.z, sg.w};
        float qq[4] = {q3.x, q3.y, q3.z, q3.w};
        int ii[4] = {in4.x, in4.y, in4.z, in4.w};
        int ll[4] = {lb4.x, lb4.y, lb4.z, lb4.w};
#pragma unroll
        for (int j = 0; j < 4; j++) {
            int pix = base + j;
            float xm = (float)(pix & (W_ - 1)) * (2.0f / 2047.0f);
            float ym = (float)(pix >> 10) * (1.0f / 1023.0f);
            float seed = fsigmoid_(qq[j]);
            if (ll[j] == 0) acc[40] += seed * seed;
            float s = ss[j];
#pragma unroll
            for (int k = 0; k < K_; k++) {
                float m = (ii[j] == k + 1) ? 1.0f : 0.0f;
                acc[k]      += m;
                acc[8 + k]  += m * xm;
                acc[16 + k] += m * ym;
                acc[24 + k] += m * s;
                acc[32 + k] += m * s * s;
            }
        }
    }
#pragma unroll
    for (int i = 0; i < 41; i++) {
        float v = acc[i];
#pragma unroll
        for (int off = 32; off; off >>= 1) v += __shfl_down(v, off, 64);
        acc[i] = v;
    }
    if ((tid & 63) == 0) {
#pragma unroll
        for (int k = 0; k < K_; k++) {
            atomicAdd(&wsf[CNT_OFF + b * K_ + k], acc[k]);
            atomicAdd(&wsf[SX_OFF  + b * K_ + k], acc[8 + k]);
            atomicAdd(&wsf[SY_OFF  + b * K_ + k], acc[16 + k]);
            atomicAdd(&wsf[SS_OFF  + b * K_ + k], acc[24 + k]);
            atomicAdd(&wsf[SS2_OFF + b * K_ + k], acc[32 + k]);
        }
        atomicAdd(&wsf[BG_OFF + b], acc[40]);
    }
}

// ---------------- Stage 2: finalize per-instance params ----------------
__global__ void finalize_kernel(float* __restrict__ wsf) {
    int i = threadIdx.x;
    if (i >= BK_) return;
    float counts = wsf[CNT_OFF + i];
    float cnt = fmaxf(counts, 1.0f);
    float cx = wsf[SX_OFF + i] / cnt;
    float cy = wsf[SY_OFF + i] / cnt;
    float smean = wsf[SS_OFF + i] / cnt;
    float var = wsf[SS2_OFF + i] / cnt - smean * smean;  // forward value of ref var_k
    float sexp = __expf(10.0f * smean * 1.442695041f * 0.6931471806f);  // = expf(10*smean)
    sexp = expf(10.0f * smean);   // keep accurate exp here (feeds every dist)
    float* fin = wsf + FIN_OFF + i * 5;
    fin[0] = cx; fin[1] = cy; fin[2] = sexp; fin[3] = counts; fin[4] = var;
}

// ---------------- Stage 3: LDS histograms -> plain-store partials ----------------
// 32 KB LDS: 8 instances x 1024 bins, packed u32 = (fg<<16 | total); per-block
// count <= 4096 < 2^16. Flush = regular coalesced stores (NO global atomics).
__global__ __launch_bounds__(512, 4) void hist_kernel(const float* __restrict__ pred,
                                                      const int* __restrict__ inst,
                                                      float* __restrict__ wsf,
                                                      unsigned int* __restrict__ partial) {
    __shared__ unsigned int hsh[KM_];   // 32 KB
    int tid = threadIdx.x;
    int b = blockIdx.x / HBPB_;
    int pix0 = (blockIdx.x % HBPB_) * HCHUNK_;

    for (int i = tid; i < KM_; i += 512) hsh[i] = 0u;

    float cx[K_], cy[K_], sxp[K_];
    bool prs[K_];
#pragma unroll
    for (int k = 0; k < K_; k++) {
        const float* fin = wsf + FIN_OFF + (b * K_ + k) * 5;
        cx[k] = fin[0]; cy[k] = fin[1]; sxp[k] = fin[2];
        prs[k] = fin[3] > 0.0f;
    }
    __syncthreads();

    const float* p0p = pred + ((long long)b * 4) * N_;
    const float* p1p = p0p + N_;
    const float* p3p = p0p + 3LL * N_;
    const int* insp = inst + (long long)b * N_;

    float sfg[K_];
#pragma unroll
    for (int k = 0; k < K_; k++) sfg[k] = 0.0f;

#pragma unroll
    for (int it = 0; it < HCHUNK_ / (512 * 4); it++) {   // 2 float4 iterations
        int base = pix0 + (it * 512 + tid) * 4;
        float4 a0 = *(const float4*)(p0p + base);
        float4 a1 = *(const float4*)(p1p + base);
        float4 a3 = *(const float4*)(p3p + base);
        int4 in4 = *(const int4*)(insp + base);
        float v0[4] = {a0.x, a0.y, a0.z, a0.w};
        float v1[4] = {a1.x, a1.y, a1.z, a1.w};
        float v3[4] = {a3.x, a3.y, a3.z, a3.w};
        int ii[4] = {in4.x, in4.y, in4.z, in4.w};
#pragma unroll
        for (int j = 0; j < 4; j++) {
            int pix = base + j;
            float sex = ftanh_(v0[j]) + (float)(pix & (W_ - 1)) * (2.0f / 2047.0f);
            float sey = ftanh_(v1[j]) + (float)(pix >> 10) * (1.0f / 1023.0f);
            float seed = fsigmoid_(v3[j]);
            int ins = ii[j];
#pragma unroll
            for (int k = 0; k < K_; k++) {
                if (prs[k]) {
                    float dx = sex - cx[k];
                    float dy = sey - cy[k];
                    float dist = __expf(-sxp[k] * (dx * dx + dy * dy));
                    bool fg = (ins == k + 1);
                    float err = fg ? (2.0f - 2.0f * dist) : (2.0f * dist);
                    int bin = (int)fminf(fmaxf(err * (float)(M_ / 2), 0.0f), (float)(M_ - 1));
                    atomicAdd(&hsh[k * M_ + bin], fg ? 0x10001u : 1u);
                    float d = seed - dist;
                    sfg[k] += fg ? d * d : 0.0f;
                }
            }
        }
    }
    __syncthreads();

    unsigned int* gp = partial + (size_t)blockIdx.x * KM_;
    for (int i = tid; i < KM_; i += 512) gp[i] = hsh[i];

#pragma unroll
    for (int k = 0; k < K_; k++) {
        float v = sfg[k];
#pragma unroll
        for (int off = 32; off; off >>= 1) v += __shfl_down(v, off, 64);
        if ((tid & 63) == 0 && v != 0.0f)
            atomicAdd(&wsf[SEEDFG_OFF + b * K_ + k], v);
    }
}

// ---------------- Stage 4: reduce partials + Lovasz suffix scan ----------------
// loss = binw * [0.5*J_0 + sum_{j>=1} J_j],  J_j = 1-(p-F_j)/(p+R_j-F_j),
// R_j,F_j = suffix sums over bins >= j.
__global__ __launch_bounds__(256) void lovasz_kernel(const unsigned int* __restrict__ partial,
                                                     float* __restrict__ wsf) {
    int bk = blockIdx.x;
    int b = bk / K_, k = bk % K_;
    int tid = threadIdx.x;

    // thread owns contiguous bins 4t..4t+3; sum over this image's 128 partials
    unsigned int n[4] = {0, 0, 0, 0}, f[4] = {0, 0, 0, 0};
    const unsigned int* base = partial + (size_t)(b * HBPB_) * KM_ + k * M_ + tid * 4;
    for (int blk = 0; blk < HBPB_; blk++) {
        uint4 v = *(const uint4*)(base + (size_t)blk * KM_);
        n[0] += v.x & 0xffffu; f[0] += v.x >> 16;
        n[1] += v.y & 0xffffu; f[1] += v.y >> 16;
        n[2] += v.z & 0xffffu; f[2] += v.z >> 16;
        n[3] += v.w & 0xffffu; f[3] += v.w >> 16;
    }

    __shared__ unsigned int sn[256], sf[256], rn[256], rf[256];
    __shared__ float sacc[256];
    sn[tid] = n[0] + n[1] + n[2] + n[3];
    sf[tid] = f[0] + f[1] + f[2] + f[3];
    __syncthreads();
    if (tid == 0) {
        unsigned int an = 0, af = 0;
        for (int t = 255; t >= 0; t--) { rn[t] = an; rf[t] = af; an += sn[t]; af += sf[t]; }
    }
    __syncthreads();

    float p = wsf[CNT_OFF + bk];
    float pp = fmaxf(p, 1.0f);
    unsigned int R = rn[tid], F = rf[tid];
    float acc = 0.0f;
#pragma unroll
    for (int j = 3; j >= 0; j--) {
        R += n[j]; F += f[j];
        float J = (R == 0) ? 0.0f : (1.0f - (pp - (float)F) / (pp + (float)(R - F)));
        acc += (tid == 0 && j == 0) ? 0.5f * J : J;
    }
    sacc[tid] = acc;
    __syncthreads();
    for (int s = 128; s > 0; s >>= 1) {
        if (tid < s) sacc[tid] += sacc[tid + s];
        __syncthreads();
    }
    if (tid == 0)
        wsf[LOV_OFF + bk] = (p > 0.0f) ? sacc[0] * (2.0f / (float)M_) : 0.0f;
}

// ---------------- Stage 5: combine (parallel) ----------------
__global__ void final_kernel(const float* __restrict__ wsf, float* __restrict__ out) {
    int tid = threadIdx.x;
    float instl = 0.0f, varl = 0.0f, sfg = 0.0f, npres = 0.0f;
    if (tid < BK_) {
        float c = wsf[CNT_OFF + tid];
        if (c > 0.0f) {
            npres = 1.0f;
            instl = wsf[LOV_OFF + tid];
            varl  = wsf[FIN_OFF + tid * 5 + 4];
            sfg   = wsf[SEEDFG_OFF + tid];
        }
    }
#pragma unroll
    for (int off = 4; off; off >>= 1) {
        instl += __shfl_down(instl, off, 8);
        varl  += __shfl_down(varl,  off, 8);
        sfg   += __shfl_down(sfg,   off, 8);
        npres += __shfl_down(npres, off, 8);
    }
    float total = 0.0f;
    if ((tid & 7) == 0 && tid < BK_) {
        int b = tid / 8;
        float objf = fmaxf(npres, 1.0f);
        float seedl = (wsf[BG_OFF + b] + sfg) / (float)N_;
        total = instl / objf + 10.0f * varl / objf + seedl;
    }
    float t0 = __shfl(total, 0, 64), t1 = __shfl(total, 8, 64);
    float t2 = __shfl(total, 16, 64), t3 = __shfl(total, 24, 64);
    if (tid == 0) out[0] = (t0 + t1 + t2 + t3) * 0.25f;
}

extern "C" void kernel_launch(void* const* d_in, const int* in_sizes, int n_in,
                              void* d_out, int out_size, void* d_ws, size_t ws_size,
                              hipStream_t stream) {
    const float* pred = (const float*)d_in[0];
    const int* inst = (const int*)d_in[1];
    const int* lab = (const int*)d_in[2];
    float* out = (float*)d_out;

    unsigned int* partial = (unsigned int*)d_ws;
    float* wsf = (float*)((char*)d_ws + PART_BYTES);

    // only the small float accumulator region needs zeroing (partials are
    // fully overwritten by hist_kernel's plain stores)
    hipMemsetAsync(wsf, 0, (size_t)FLOATS_TOTAL * 4, stream);

    stats_kernel<<<SB_, 256, 0, stream>>>(pred, inst, lab, wsf);
    finalize_kernel<<<1, 64, 0, stream>>>(wsf);
    hist_kernel<<<HB_, 512, 0, stream>>>(pred, inst, wsf, partial);
    lovasz_kernel<<<BK_, 256, 0, stream>>>(partial, wsf);
    final_kernel<<<1, 64, 0, stream>>>(wsf, out);
}

// Round 4
// 309.713 us; speedup vs baseline: 2.5664x; 2.5664x over previous
//
#include <hip/hip_runtime.h>
#include <math.h>

namespace {
constexpr int B_ = 4, K_ = 8, H_ = 512, W_ = 1024;
constexpr int N_ = H_ * W_;            // 524288 pixels per image
constexpr int M_ = 1024;               // err histogram bins over [0,2]
constexpr int BK_ = B_ * K_;
constexpr int KM_ = K_ * M_;           // 8192 bins per hist block (32 KB LDS)

constexpr int HB_ = 512;               // hist blocks (128 per image)
constexpr int HBPB_ = HB_ / B_;
constexpr int HCHUNK_ = B_ * N_ / HB_; // 4096 pixels per block
constexpr int SB_ = 512;               // stats blocks (128 per image)
constexpr int SBPB_ = SB_ / B_;
constexpr int SCHUNK_ = B_ * N_ / SB_; // 4096 pixels per block
constexpr int NSTAT = 41;              // 8 inst x {cnt,xm,ym,s,s2} + bg

// workspace layout (bytes)
constexpr size_t PART_BYTES = (size_t)HB_ * KM_ * 4;            // 16 MB hist partials
constexpr size_t RED_OFF_B  = PART_BYTES;                       // uint2[BK_*M_] = 256 KB
constexpr size_t PSTAT_OFF_B = RED_OFF_B + (size_t)BK_ * M_ * 8;
constexpr size_t WSF_OFF_B  = PSTAT_OFF_B + (size_t)SB_ * NSTAT * 4;

// float accumulator region offsets (floats)
constexpr int CNT_OFF = 0;             // 32: per-(b,k) pixel counts
constexpr int BG_OFF = 32;             // 4:  per-image bg seed loss
constexpr int SEEDFG_OFF = 36;         // 32
constexpr int LOV_OFF = 68;            // 32
constexpr int FIN_OFF = 100;           // 5 per (b,k): cx,cy,sexp,counts,var
}

__device__ __forceinline__ float fsigmoid_(float x) { return 1.0f / (1.0f + __expf(-x)); }
__device__ __forceinline__ float ftanh_(float x) { return 1.0f - 2.0f / (__expf(2.0f * x) + 1.0f); }

// ---- Stage 1: per-instance stats via per-wave LDS accumulators, plain-store partials ----
__global__ __launch_bounds__(256) void stats_kernel(const float* __restrict__ pred,
                                                    const int* __restrict__ inst,
                                                    const int* __restrict__ lab,
                                                    float* __restrict__ pstat) {
    __shared__ float sacc[4 * 48];     // 4 waves x 48-slot region (slots 0..40 used)
    int tid = threadIdx.x;
    for (int i = tid; i < 4 * 48; i += 256) sacc[i] = 0.0f;
    __syncthreads();

    int b = blockIdx.x / SBPB_;
    int pix0 = (blockIdx.x % SBPB_) * SCHUNK_;
    float* wacc = sacc + (tid >> 6) * 48;

    const float* sigp = pred + ((long long)b * 4 + 2) * N_;
    const float* p3p  = pred + ((long long)b * 4 + 3) * N_;
    const int*   insp = inst + (long long)b * N_;
    const int*   labp = lab  + (long long)b * N_;

    float bgacc = 0.0f;
#pragma unroll
    for (int it = 0; it < SCHUNK_ / (256 * 4); it++) {   // 4 float4 iterations
        int base = pix0 + (it * 256 + tid) * 4;
        float4 sg = *(const float4*)(sigp + base);
        float4 q3 = *(const float4*)(p3p + base);
        int4 in4 = *(const int4*)(insp + base);
        int4 lb4 = *(const int4*)(labp + base);
        float ss[4] = {sg.x, sg.y, sg.z, sg.w};
        float qq[4] = {q3.x, q3.y, q3.z, q3.w};
        int ii[4] = {in4.x, in4.y, in4.z, in4.w};
        int ll[4] = {lb4.x, lb4.y, lb4.z, lb4.w};
#pragma unroll
        for (int j = 0; j < 4; j++) {
            float seed = fsigmoid_(qq[j]);
            if (ll[j] == 0) bgacc += seed * seed;
            int ins = ii[j];
            if (ins > 0) {                               // pixel belongs to exactly one instance
                int pix = base + j;
                float xm = (float)(pix & (W_ - 1)) * (2.0f / 2047.0f);
                float ym = (float)(pix >> 10) * (1.0f / 1023.0f);
                float s = ss[j];
                int s0 = (ins - 1) * 5;
                atomicAdd(&wacc[s0], 1.0f);
                atomicAdd(&wacc[s0 + 1], xm);
                atomicAdd(&wacc[s0 + 2], ym);
                atomicAdd(&wacc[s0 + 3], s);
                atomicAdd(&wacc[s0 + 4], s * s);
            }
        }
    }
#pragma unroll
    for (int off = 32; off; off >>= 1) bgacc += __shfl_down(bgacc, off, 64);
    if ((tid & 63) == 0) wacc[40] += bgacc;              // one lane per wave, private region
    __syncthreads();

    if (tid < NSTAT)
        pstat[blockIdx.x * NSTAT + tid] =
            sacc[tid] + sacc[48 + tid] + sacc[96 + tid] + sacc[144 + tid];
}

// ---- Stage 2: reduce stat partials, compute per-instance params ----
__global__ void finalize_kernel(const float* __restrict__ pstat, float* __restrict__ wsf) {
    __shared__ float sums[4][NSTAT];
    int t = threadIdx.x;   // 256
    if (t < B_ * NSTAT) {
        int b = t / NSTAT, st = t % NSTAT;
        const float* p = pstat + (size_t)(b * SBPB_) * NSTAT + st;
        float v = 0.0f;
        for (int j = 0; j < SBPB_; j++) v += p[(size_t)j * NSTAT];
        sums[b][st] = v;
    }
    __syncthreads();
    if (t < BK_) {
        int b = t >> 3, k = t & 7;
        float counts = sums[b][k * 5];
        float cnt = fmaxf(counts, 1.0f);
        float cx = sums[b][k * 5 + 1] / cnt;
        float cy = sums[b][k * 5 + 2] / cnt;
        float smean = sums[b][k * 5 + 3] / cnt;
        float var = sums[b][k * 5 + 4] / cnt - smean * smean;  // fwd value of ref var_k
        float* fin = wsf + FIN_OFF + t * 5;
        fin[0] = cx; fin[1] = cy; fin[2] = expf(10.0f * smean);
        fin[3] = counts; fin[4] = var;
        wsf[CNT_OFF + t] = counts;
        wsf[SEEDFG_OFF + t] = 0.0f;                      // zero for hist's atomics
    }
    if (t < B_) wsf[BG_OFF + t] = sums[t][40];
}

// ---- Stage 3: LDS histograms (8x1024 bins, fg<<16|total) -> plain-store partials ----
__global__ __launch_bounds__(256) void hist_kernel(const float* __restrict__ pred,
                                                   const int* __restrict__ inst,
                                                   const float* __restrict__ wsf,
                                                   unsigned int* __restrict__ partial) {
    __shared__ unsigned int hsh[KM_];   // 32 KB
    int tid = threadIdx.x;
    int b = blockIdx.x / HBPB_;
    int pix0 = (blockIdx.x % HBPB_) * HCHUNK_;

    for (int i = tid; i < KM_; i += 256) hsh[i] = 0u;

    float cx[K_], cy[K_], sxp[K_];
    bool prs[K_];
#pragma unroll
    for (int k = 0; k < K_; k++) {
        const float* fin = wsf + FIN_OFF + (b * K_ + k) * 5;
        cx[k] = fin[0]; cy[k] = fin[1]; sxp[k] = fin[2];
        prs[k] = fin[3] > 0.0f;
    }
    __syncthreads();

    const float* p0p = pred + ((long long)b * 4) * N_;
    const float* p1p = p0p + N_;
    const float* p3p = p0p + 3LL * N_;
    const int* insp = inst + (long long)b * N_;

    float sfg[K_];
#pragma unroll
    for (int k = 0; k < K_; k++) sfg[k] = 0.0f;

#pragma unroll
    for (int it = 0; it < HCHUNK_ / (256 * 4); it++) {   // 4 float4 iterations
        int base = pix0 + (it * 256 + tid) * 4;
        float4 a0 = *(const float4*)(p0p + base);
        float4 a1 = *(const float4*)(p1p + base);
        float4 a3 = *(const float4*)(p3p + base);
        int4 in4 = *(const int4*)(insp + base);
        float v0[4] = {a0.x, a0.y, a0.z, a0.w};
        float v1[4] = {a1.x, a1.y, a1.z, a1.w};
        float v3[4] = {a3.x, a3.y, a3.z, a3.w};
        int ii[4] = {in4.x, in4.y, in4.z, in4.w};
#pragma unroll
        for (int j = 0; j < 4; j++) {
            int pix = base + j;
            float sex = ftanh_(v0[j]) + (float)(pix & (W_ - 1)) * (2.0f / 2047.0f);
            float sey = ftanh_(v1[j]) + (float)(pix >> 10) * (1.0f / 1023.0f);
            float seed = fsigmoid_(v3[j]);
            int ins = ii[j];
#pragma unroll
            for (int k = 0; k < K_; k++) {
                if (prs[k]) {
                    float dx = sex - cx[k];
                    float dy = sey - cy[k];
                    float dist = __expf(-sxp[k] * (dx * dx + dy * dy));
                    bool fg = (ins == k + 1);
                    float err = fg ? (2.0f - 2.0f * dist) : (2.0f * dist);
                    int bin = (int)fminf(fmaxf(err * (float)(M_ / 2), 0.0f), (float)(M_ - 1));
                    atomicAdd(&hsh[k * M_ + bin], fg ? 0x10001u : 1u);
                    float d = seed - dist;
                    sfg[k] += fg ? d * d : 0.0f;
                }
            }
        }
    }
    __syncthreads();

    uint4* gp = (uint4*)(partial + (size_t)blockIdx.x * KM_);
    const uint4* hs4 = (const uint4*)hsh;
    for (int i = tid; i < KM_ / 4; i += 256) gp[i] = hs4[i];

#pragma unroll
    for (int k = 0; k < K_; k++) {
        float v = sfg[k];
#pragma unroll
        for (int off = 32; off; off >>= 1) v += __shfl_down(v, off, 64);
        if ((tid & 63) == 0 && v != 0.0f)
            atomicAdd((float*)wsf + SEEDFG_OFF + b * K_ + k, v);
    }
}

// ---- Stage 4: reduce hist partials: 128 blocks, each (b,k,256-bin slice) ----
__global__ __launch_bounds__(256) void reduce_kernel(const unsigned int* __restrict__ partial,
                                                     uint2* __restrict__ red) {
    int bk = blockIdx.x >> 2;
    int slice = blockIdx.x & 3;
    int b = bk >> 3, k = bk & 7;
    int bin = slice * 256 + threadIdx.x;
    const unsigned int* p = partial + (size_t)(b * HBPB_) * KM_ + k * M_ + bin;
    unsigned int n = 0, f = 0;
    for (int j = 0; j < HBPB_; j++) {
        unsigned int v = p[(size_t)j * KM_];
        n += v & 0xffffu;
        f += v >> 16;
    }
    red[bk * M_ + bin] = make_uint2(n, f);
}

// ---- Stage 5: Lovasz via histogram suffix scan ----
// loss = binw * [0.5*J_0 + sum_{j>=1} J_j], J_j = 1-(p-F_j)/(p+R_j-F_j),
// R,F = suffix sums over bins >= j (verified exact vs ref at M=1024/2048).
__global__ __launch_bounds__(256) void lovasz_kernel(const uint2* __restrict__ red,
                                                     float* __restrict__ wsf) {
    int bk = blockIdx.x;
    int tid = threadIdx.x;

    const uint4* hh = (const uint4*)(red + bk * M_) + tid * 2;
    uint4 va = hh[0], vb = hh[1];
    unsigned int n[4] = {va.x, va.z, vb.x, vb.z};
    unsigned int f[4] = {va.y, va.w, vb.y, vb.w};

    __shared__ unsigned int sn[256], sf[256], rn[256], rf[256];
    __shared__ float sacc[256];
    sn[tid] = n[0] + n[1] + n[2] + n[3];
    sf[tid] = f[0] + f[1] + f[2] + f[3];
    __syncthreads();
    if (tid == 0) {
        unsigned int an = 0, af = 0;
        for (int t = 255; t >= 0; t--) { rn[t] = an; rf[t] = af; an += sn[t]; af += sf[t]; }
    }
    __syncthreads();

    float p = wsf[CNT_OFF + bk];
    float pp = fmaxf(p, 1.0f);
    unsigned int R = rn[tid], F = rf[tid];
    float acc = 0.0f;
#pragma unroll
    for (int j = 3; j >= 0; j--) {
        R += n[j]; F += f[j];
        float J = (R == 0) ? 0.0f : (1.0f - (pp - (float)F) / (pp + (float)(R - F)));
        acc += (tid == 0 && j == 0) ? 0.5f * J : J;
    }
    sacc[tid] = acc;
    __syncthreads();
    for (int s = 128; s > 0; s >>= 1) {
        if (tid < s) sacc[tid] += sacc[tid + s];
        __syncthreads();
    }
    if (tid == 0)
        wsf[LOV_OFF + bk] = (p > 0.0f) ? sacc[0] * (2.0f / (float)M_) : 0.0f;
}

// ---- Stage 6: combine ----
__global__ void final_kernel(const float* __restrict__ wsf, float* __restrict__ out) {
    int tid = threadIdx.x;
    float instl = 0.0f, varl = 0.0f, sfg = 0.0f, npres = 0.0f;
    if (tid < BK_) {
        float c = wsf[CNT_OFF + tid];
        if (c > 0.0f) {
            npres = 1.0f;
            instl = wsf[LOV_OFF + tid];
            varl  = wsf[FIN_OFF + tid * 5 + 4];
            sfg   = wsf[SEEDFG_OFF + tid];
        }
    }
#pragma unroll
    for (int off = 4; off; off >>= 1) {
        instl += __shfl_down(instl, off, 8);
        varl  += __shfl_down(varl,  off, 8);
        sfg   += __shfl_down(sfg,   off, 8);
        npres += __shfl_down(npres, off, 8);
    }
    float total = 0.0f;
    if ((tid & 7) == 0 && tid < BK_) {
        int b = tid / 8;
        float objf = fmaxf(npres, 1.0f);
        float seedl = (wsf[BG_OFF + b] + sfg) / (float)N_;
        total = instl / objf + 10.0f * varl / objf + seedl;
    }
    float t0 = __shfl(total, 0, 64), t1 = __shfl(total, 8, 64);
    float t2 = __shfl(total, 16, 64), t3 = __shfl(total, 24, 64);
    if (tid == 0) out[0] = (t0 + t1 + t2 + t3) * 0.25f;
}

extern "C" void kernel_launch(void* const* d_in, const int* in_sizes, int n_in,
                              void* d_out, int out_size, void* d_ws, size_t ws_size,
                              hipStream_t stream) {
    const float* pred = (const float*)d_in[0];
    const int* inst = (const int*)d_in[1];
    const int* lab = (const int*)d_in[2];
    float* out = (float*)d_out;

    unsigned int* partial = (unsigned int*)d_ws;
    uint2* red = (uint2*)((char*)d_ws + RED_OFF_B);
    float* pstat = (float*)((char*)d_ws + PSTAT_OFF_B);
    float* wsf = (float*)((char*)d_ws + WSF_OFF_B);

    // no memset: every workspace region is fully written before it is read
    // (finalize zeroes SEEDFG; partials/red/pstat are plain-store overwritten)
    stats_kernel<<<SB_, 256, 0, stream>>>(pred, inst, lab, pstat);
    finalize_kernel<<<1, 256, 0, stream>>>(pstat, wsf);
    hist_kernel<<<HB_, 256, 0, stream>>>(pred, inst, wsf, partial);
    reduce_kernel<<<BK_ * 4, 256, 0, stream>>>(partial, red);
    lovasz_kernel<<<BK_, 256, 0, stream>>>(red, wsf);
    final_kernel<<<1, 64, 0, stream>>>(wsf, out);
}

// Round 6
// 147.198 us; speedup vs baseline: 5.3998x; 2.1041x over previous
//
#include <hip/hip_runtime.h>
#include <math.h>

namespace {
constexpr int B_ = 4, K_ = 8, H_ = 512, W_ = 1024;
constexpr int N_ = H_ * W_;             // 524288 pixels per image
constexpr int M_ = 256;                 // err histogram bins over [0,2]
constexpr int BK_ = B_ * K_;
constexpr int KM_ = K_ * M_;            // 2048 bins per hist block (8 KB LDS)

constexpr int HB_ = 2048;               // hist blocks
constexpr int HBPB_ = HB_ / B_;         // 512 per image
constexpr int HCH_ = N_ / HBPB_;        // 1024 pixels per block
constexpr int SB_ = 1024;               // stats blocks
constexpr int SBPB_ = SB_ / B_;         // 256 per image
constexpr int SCH_ = N_ / SBPB_;        // 2048 pixels per block
constexpr int NSTAT = 41;               // interleaved: k*5+{cnt,xm,ym,s,s2}, [40]=bg

// workspace layout (bytes)
constexpr size_t PART_BYTES  = (size_t)HB_ * KM_ * 4;          // 16 MB
constexpr size_t SFG_OFF_B   = PART_BYTES;                     // 32*512 floats
constexpr size_t PSTAT_OFF_B = SFG_OFF_B + (size_t)BK_ * HBPB_ * 4;
constexpr size_t WSF_OFF_B   = PSTAT_OFF_B + (size_t)B_ * NSTAT * SBPB_ * 4;

// wsf float offsets
constexpr int CNT_OFF = 0;              // 32 per-(b,k) counts
constexpr int BG_OFF  = 32;             // 4 per-image bg seed loss
constexpr int LOV_OFF = 36;             // 32
constexpr int FIN_OFF = 68;             // 5 per (b,k): cx,cy,sexp,counts,var
}

__device__ __forceinline__ float fsigmoid_(float x) { return 1.0f / (1.0f + __expf(-x)); }
__device__ __forceinline__ float ftanh_(float x) { return 1.0f - 2.0f / (__expf(2.0f * x) + 1.0f); }

// ---- Stage 1: per-instance stats, register masked-FMA accumulators ----
// LAYOUT CONTRACT (must match finalize_kernel): acc[k*5+0..4] =
// {count, sum_xm, sum_ym, sum_s, sum_s2} for instance k; acc[40] = bg seed^2.
__global__ __launch_bounds__(256) void stats_kernel(const float* __restrict__ pred,
                                                    const int* __restrict__ inst,
                                                    const int* __restrict__ lab,
                                                    float* __restrict__ pstat) {
    int tid = threadIdx.x;
    int b = blockIdx.x >> 8;            // SBPB_ = 256 blocks per image
    int blk = blockIdx.x & (SBPB_ - 1);
    int pix0 = blk * SCH_;

    const float* sigp = pred + ((long long)b * 4 + 2) * N_;
    const float* p3p  = pred + ((long long)b * 4 + 3) * N_;
    const int*   insp = inst + (long long)b * N_;
    const int*   labp = lab  + (long long)b * N_;

    float acc[NSTAT];
#pragma unroll
    for (int i = 0; i < NSTAT; i++) acc[i] = 0.0f;

#pragma unroll
    for (int it = 0; it < SCH_ / (256 * 4); it++) {   // 2 float4 iterations
        int base = pix0 + (it * 256 + tid) * 4;
        float4 sg = *(const float4*)(sigp + base);
        float4 q3 = *(const float4*)(p3p + base);
        int4 in4 = *(const int4*)(insp + base);
        int4 lb4 = *(const int4*)(labp + base);
        float ss[4] = {sg.x, sg.y, sg.z, sg.w};
        float qq[4] = {q3.x, q3.y, q3.z, q3.w};
        int ii[4] = {in4.x, in4.y, in4.z, in4.w};
        int ll[4] = {lb4.x, lb4.y, lb4.z, lb4.w};
#pragma unroll
        for (int j = 0; j < 4; j++) {
            int pix = base + j;
            float xm = (float)(pix & (W_ - 1)) * (2.0f / 2047.0f);
            float ym = (float)(pix >> 10) * (1.0f / 1023.0f);
            float seed = fsigmoid_(qq[j]);
            if (ll[j] == 0) acc[40] += seed * seed;
            float s = ss[j];
#pragma unroll
            for (int k = 0; k < K_; k++) {            // interleaved layout
                float m = (ii[j] == k + 1) ? 1.0f : 0.0f;
                acc[k * 5]     += m;
                acc[k * 5 + 1] += m * xm;
                acc[k * 5 + 2] += m * ym;
                acc[k * 5 + 3] += m * s;
                acc[k * 5 + 4] += m * s * s;
            }
        }
    }
    // wave reduce all 41, then cross-wave via LDS
#pragma unroll
    for (int i = 0; i < NSTAT; i++) {
        float v = acc[i];
#pragma unroll
        for (int off = 32; off; off >>= 1) v += __shfl_down(v, off, 64);
        acc[i] = v;
    }
    __shared__ float xw[4][NSTAT];
    if ((tid & 63) == 0) {
        int w = tid >> 6;
#pragma unroll
        for (int i = 0; i < NSTAT; i++) xw[w][i] = acc[i];
    }
    __syncthreads();
    if (tid < NSTAT)
        pstat[((b * NSTAT + tid) << 8) + blk] =
            xw[0][tid] + xw[1][tid] + xw[2][tid] + xw[3][tid];
}

// ---- Stage 2: reduce stat partials (contiguous, ILP), per-instance params ----
__global__ void finalize_kernel(const float* __restrict__ pstat, float* __restrict__ wsf) {
    __shared__ float sums[B_][NSTAT];
    int t = threadIdx.x;   // 256
    if (t < B_ * NSTAT) {
        const float* p = pstat + ((size_t)t << 8);    // t = b*NSTAT+st, 256 contiguous
        float v0 = 0, v1 = 0, v2 = 0, v3 = 0;
        for (int j = 0; j < SBPB_; j += 4) {
            v0 += p[j]; v1 += p[j + 1]; v2 += p[j + 2]; v3 += p[j + 3];
        }
        sums[t / NSTAT][t % NSTAT] = (v0 + v1) + (v2 + v3);
    }
    __syncthreads();
    if (t < BK_) {
        int b = t >> 3, k = t & 7;
        float counts = sums[b][k * 5];                // interleaved layout
        float cnt = fmaxf(counts, 1.0f);
        float smean = sums[b][k * 5 + 3] / cnt;
        float* fin = wsf + FIN_OFF + t * 5;
        fin[0] = sums[b][k * 5 + 1] / cnt;            // cx
        fin[1] = sums[b][k * 5 + 2] / cnt;            // cy
        fin[2] = expf(10.0f * smean);                 // sexp (accurate: feeds every dist)
        fin[3] = counts;
        fin[4] = sums[b][k * 5 + 4] / cnt - smean * smean;  // var (fwd value)
        wsf[CNT_OFF + t] = counts;
    }
    if (t < B_) wsf[BG_OFF + t] = sums[t][40];
}

// ---- Stage 3: LDS histograms (8x256 bins, fg<<16|total), plain-store partials ----
__global__ __launch_bounds__(256) void hist_kernel(const float* __restrict__ pred,
                                                   const int* __restrict__ inst,
                                                   const float* __restrict__ wsf,
                                                   unsigned int* __restrict__ partial,
                                                   float* __restrict__ sfgpart) {
    __shared__ unsigned int hsh[KM_];   // 8 KB
    __shared__ float xfg[4][K_];
    int tid = threadIdx.x;
    int b = blockIdx.x >> 9;            // HBPB_ = 512 blocks per image
    int blk = blockIdx.x & (HBPB_ - 1);
    int pix0 = blk * HCH_;

#pragma unroll
    for (int i = tid; i < KM_; i += 256) hsh[i] = 0u;

    float cx[K_], cy[K_], sxp[K_];
    bool prs[K_];
#pragma unroll
    for (int k = 0; k < K_; k++) {
        const float* fin = wsf + FIN_OFF + (b * K_ + k) * 5;
        cx[k] = fin[0]; cy[k] = fin[1]; sxp[k] = fin[2];
        prs[k] = fin[3] > 0.0f;
    }
    __syncthreads();

    const float* p0p = pred + ((long long)b * 4) * N_;
    const float* p1p = p0p + N_;
    const float* p3p = p0p + 3LL * N_;
    const int* insp = inst + (long long)b * N_;

    float sfg[K_];
#pragma unroll
    for (int k = 0; k < K_; k++) sfg[k] = 0.0f;

    {   // one float4 iteration: 4 pixels per thread
        int base = pix0 + tid * 4;
        float4 a0 = *(const float4*)(p0p + base);
        float4 a1 = *(const float4*)(p1p + base);
        float4 a3 = *(const float4*)(p3p + base);
        int4 in4 = *(const int4*)(insp + base);
        float v0[4] = {a0.x, a0.y, a0.z, a0.w};
        float v1[4] = {a1.x, a1.y, a1.z, a1.w};
        float v3[4] = {a3.x, a3.y, a3.z, a3.w};
        int ii[4] = {in4.x, in4.y, in4.z, in4.w};
#pragma unroll
        for (int j = 0; j < 4; j++) {
            int pix = base + j;
            float sex = ftanh_(v0[j]) + (float)(pix & (W_ - 1)) * (2.0f / 2047.0f);
            float sey = ftanh_(v1[j]) + (float)(pix >> 10) * (1.0f / 1023.0f);
            float seed = fsigmoid_(v3[j]);
            int ins = ii[j];
#pragma unroll
            for (int k = 0; k < K_; k++) {
                if (prs[k]) {
                    float dx = sex - cx[k];
                    float dy = sey - cy[k];
                    float dist = __expf(-sxp[k] * (dx * dx + dy * dy));
                    bool fg = (ins == k + 1);
                    float err = fg ? (2.0f - 2.0f * dist) : (2.0f * dist);
                    int bin = (int)fminf(fmaxf(err * (float)(M_ / 2), 0.0f), (float)(M_ - 1));
                    atomicAdd(&hsh[k * M_ + bin], fg ? 0x10001u : 1u);
                    float d = seed - dist;
                    sfg[k] += fg ? d * d : 0.0f;
                }
            }
        }
    }
    __syncthreads();

    uint4* gp = (uint4*)(partial + (size_t)blockIdx.x * KM_);
    const uint4* hs4 = (const uint4*)hsh;
#pragma unroll
    for (int i = tid; i < KM_ / 4; i += 256) gp[i] = hs4[i];

    // seed_fg: wave shfl reduce -> cross-wave LDS -> plain store (no atomics)
#pragma unroll
    for (int k = 0; k < K_; k++) {
        float v = sfg[k];
#pragma unroll
        for (int off = 32; off; off >>= 1) v += __shfl_down(v, off, 64);
        sfg[k] = v;
    }
    if ((tid & 63) == 0) {
        int w = tid >> 6;
#pragma unroll
        for (int k = 0; k < K_; k++) xfg[w][k] = sfg[k];
    }
    __syncthreads();
    if (tid < K_)
        sfgpart[(size_t)(b * K_ + tid) * HBPB_ + blk] =
            xfg[0][tid] + xfg[1][tid] + xfg[2][tid] + xfg[3][tid];
}

// ---- Stage 4: reduce hist partials + Lovasz suffix scan (one block per (b,k)) ----
// loss = binw * [0.5*J_0 + sum_{j>=1} J_j], J_j = 1-(p-F_j)/(p+R_j-F_j),
// R,F = suffix sums over bins >= j.
__global__ __launch_bounds__(256) void lovasz_kernel(const unsigned int* __restrict__ partial,
                                                     float* __restrict__ wsf) {
    int bk = blockIdx.x;
    int b = bk >> 3, k = bk & 7;
    int tid = threadIdx.x;              // = bin (M_ == 256)

    const unsigned int* p = partial + (size_t)(b * HBPB_) * KM_ + k * M_ + tid;
    unsigned int n = 0, f = 0;
#pragma unroll 8
    for (int j = 0; j < HBPB_; j++) {   // coalesced: 64 lanes read 256B per j
        unsigned int v = p[(size_t)j * KM_];
        n += v & 0xffffu;
        f += v >> 16;
    }

    __shared__ unsigned int sn[256], sf[256], rn[256], rf[256];
    __shared__ float sacc[256];
    sn[tid] = n; sf[tid] = f;
    __syncthreads();
    if (tid == 0) {                     // exclusive suffix scan (tiny)
        unsigned int an = 0, af = 0;
        for (int t = 255; t >= 0; t--) { rn[t] = an; rf[t] = af; an += sn[t]; af += sf[t]; }
    }
    __syncthreads();

    float pcnt = wsf[CNT_OFF + bk];
    float pp = fmaxf(pcnt, 1.0f);
    unsigned int R = rn[tid] + n, F = rf[tid] + f;
    float J = (R == 0) ? 0.0f : (1.0f - (pp - (float)F) / (pp + (float)(R - F)));
    sacc[tid] = (tid == 0 ? 0.5f : 1.0f) * J;
    __syncthreads();
    for (int s = 128; s > 0; s >>= 1) {
        if (tid < s) sacc[tid] += sacc[tid + s];
        __syncthreads();
    }
    if (tid == 0)
        wsf[LOV_OFF + bk] = (pcnt > 0.0f) ? sacc[0] * (2.0f / (float)M_) : 0.0f;
}

// ---- Stage 5: combine (reduce seed_fg partials + weighted sum) ----
__global__ void final_kernel(const float* __restrict__ wsf,
                             const float* __restrict__ sfgpart,
                             float* __restrict__ out) {
    __shared__ float sred[256];
    int t = threadIdx.x;
    {
        int bk = t >> 3, jg = t & 7;
        const float* p = sfgpart + (size_t)bk * HBPB_ + jg;
        float v = 0.0f;
        for (int i = 0; i < HBPB_ / 8; i++) v += p[i * 8];
        sred[t] = v;
    }
    __syncthreads();

    float instl = 0.0f, varl = 0.0f, sfg = 0.0f, npres = 0.0f;
    if (t < BK_) {
        float c = wsf[CNT_OFF + t];
        if (c > 0.0f) {
            npres = 1.0f;
            instl = wsf[LOV_OFF + t];
            varl  = wsf[FIN_OFF + t * 5 + 4];
            sfg = (sred[t * 8] + sred[t * 8 + 1] + sred[t * 8 + 2] + sred[t * 8 + 3]) +
                  (sred[t * 8 + 4] + sred[t * 8 + 5] + sred[t * 8 + 6] + sred[t * 8 + 7]);
        }
    }
#pragma unroll
    for (int off = 4; off; off >>= 1) {
        instl += __shfl_down(instl, off, 8);
        varl  += __shfl_down(varl,  off, 8);
        sfg   += __shfl_down(sfg,   off, 8);
        npres += __shfl_down(npres, off, 8);
    }
    float total = 0.0f;
    if ((t & 7) == 0 && t < BK_) {
        int b = t >> 3;
        float objf = fmaxf(npres, 1.0f);
        float seedl = (wsf[BG_OFF + b] + sfg) / (float)N_;
        total = instl / objf + 10.0f * varl / objf + seedl;
    }
    float t0 = __shfl(total, 0, 64), t1 = __shfl(total, 8, 64);
    float t2 = __shfl(total, 16, 64), t3 = __shfl(total, 24, 64);
    if (t == 0) out[0] = (t0 + t1 + t2 + t3) * 0.25f;
}

extern "C" void kernel_launch(void* const* d_in, const int* in_sizes, int n_in,
                              void* d_out, int out_size, void* d_ws, size_t ws_size,
                              hipStream_t stream) {
    const float* pred = (const float*)d_in[0];
    const int* inst = (const int*)d_in[1];
    const int* lab = (const int*)d_in[2];
    float* out = (float*)d_out;

    unsigned int* partial = (unsigned int*)d_ws;
    float* sfgpart = (float*)((char*)d_ws + SFG_OFF_B);
    float* pstat = (float*)((char*)d_ws + PSTAT_OFF_B);
    float* wsf = (float*)((char*)d_ws + WSF_OFF_B);

    // no memset: every workspace region is fully written before it is read
    stats_kernel<<<SB_, 256, 0, stream>>>(pred, inst, lab, pstat);
    finalize_kernel<<<1, 256, 0, stream>>>(pstat, wsf);
    hist_kernel<<<HB_, 256, 0, stream>>>(pred, inst, wsf, partial, sfgpart);
    lovasz_kernel<<<BK_, 256, 0, stream>>>(partial, wsf);
    final_kernel<<<1, 256, 0, stream>>>(wsf, sfgpart, out);
}

// Round 7
// 127.381 us; speedup vs baseline: 6.2399x; 1.1556x over previous
//
#include <hip/hip_runtime.h>
#include <math.h>

namespace {
constexpr int B_ = 4, K_ = 8, H_ = 512, W_ = 1024;
constexpr int N_ = H_ * W_;             // 524288 pixels per image
constexpr int M_ = 256;                 // err histogram bins over [0,2]
constexpr int MP_ = M_ + 1;             // padded LDS row (bank spread across k)
constexpr int BK_ = B_ * K_;
constexpr int KM_ = K_ * M_;            // 2048 bins per hist block partial

constexpr int HB_ = 1024;               // hist blocks
constexpr int HBPB_ = HB_ / B_;         // 256 per image
constexpr int HCH_ = N_ / HBPB_;        // 2048 pixels per block (2 float4 iters)
constexpr int SB_ = 1024;               // stats blocks
constexpr int SBPB_ = SB_ / B_;         // 256 per image
constexpr int SCH_ = N_ / SBPB_;        // 2048 pixels per block
constexpr int NSTAT = 41;               // interleaved k*5+{cnt,xm,ym,s,s2}, [40]=bg
constexpr int SLICES_ = 8;              // reduce1: 8 slices of 32 hist-blocks

// workspace layout (bytes)
constexpr size_t PART_BYTES  = (size_t)HB_ * KM_ * 4;            // 8 MB
constexpr size_t SFG_OFF_B   = PART_BYTES;                       // 32*256 floats
constexpr size_t RED_OFF_B   = SFG_OFF_B + (size_t)BK_ * HBPB_ * 4;
constexpr size_t PSTAT_OFF_B = RED_OFF_B + (size_t)BK_ * SLICES_ * M_ * 8;
constexpr size_t WSF_OFF_B   = PSTAT_OFF_B + (size_t)B_ * NSTAT * SBPB_ * 4;

// wsf float offsets
constexpr int CNT_OFF  = 0;             // 32 per-(b,k) counts
constexpr int BG_OFF   = 32;            // 4
constexpr int OBJF_OFF = 36;            // 4 per-image objf
constexpr int FIN_OFF  = 40;            // 5 per (b,k): cx,cy,sexp,counts,var
constexpr float LN256_ = 5.5451774445f; // ln(256): dist<1/256 <=> bg bin 0
}

__device__ __forceinline__ float fsigmoid_(float x) { return 1.0f / (1.0f + __expf(-x)); }
__device__ __forceinline__ float ftanh_(float x) { return 1.0f - 2.0f / (__expf(2.0f * x) + 1.0f); }

// ---- Stage 1: per-instance stats, register masked-FMA accumulators ----
// LAYOUT CONTRACT (matches finalize): acc[k*5+0..4]={cnt,xm,ym,s,s2}, acc[40]=bg.
__global__ __launch_bounds__(256) void stats_kernel(const float* __restrict__ pred,
                                                    const int* __restrict__ inst,
                                                    const int* __restrict__ lab,
                                                    float* __restrict__ pstat) {
    int tid = threadIdx.x;
    int b = blockIdx.x >> 8;
    int blk = blockIdx.x & (SBPB_ - 1);
    int pix0 = blk * SCH_;

    const float* sigp = pred + ((long long)b * 4 + 2) * N_;
    const float* p3p  = pred + ((long long)b * 4 + 3) * N_;
    const int*   insp = inst + (long long)b * N_;
    const int*   labp = lab  + (long long)b * N_;

    float acc[NSTAT];
#pragma unroll
    for (int i = 0; i < NSTAT; i++) acc[i] = 0.0f;

#pragma unroll
    for (int it = 0; it < SCH_ / (256 * 4); it++) {
        int base = pix0 + (it * 256 + tid) * 4;
        float4 sg = *(const float4*)(sigp + base);
        float4 q3 = *(const float4*)(p3p + base);
        int4 in4 = *(const int4*)(insp + base);
        int4 lb4 = *(const int4*)(labp + base);
        float ss[4] = {sg.x, sg.y, sg.z, sg.w};
        float qq[4] = {q3.x, q3.y, q3.z, q3.w};
        int ii[4] = {in4.x, in4.y, in4.z, in4.w};
        int ll[4] = {lb4.x, lb4.y, lb4.z, lb4.w};
#pragma unroll
        for (int j = 0; j < 4; j++) {
            int pix = base + j;
            float xm = (float)(pix & (W_ - 1)) * (2.0f / 2047.0f);
            float ym = (float)(pix >> 10) * (1.0f / 1023.0f);
            float seed = fsigmoid_(qq[j]);
            if (ll[j] == 0) acc[40] += seed * seed;
            float s = ss[j];
#pragma unroll
            for (int k = 0; k < K_; k++) {
                float m = (ii[j] == k + 1) ? 1.0f : 0.0f;
                acc[k * 5]     += m;
                acc[k * 5 + 1] += m * xm;
                acc[k * 5 + 2] += m * ym;
                acc[k * 5 + 3] += m * s;
                acc[k * 5 + 4] += m * s * s;
            }
        }
    }
#pragma unroll
    for (int i = 0; i < NSTAT; i++) {
        float v = acc[i];
#pragma unroll
        for (int off = 32; off; off >>= 1) v += __shfl_down(v, off, 64);
        acc[i] = v;
    }
    __shared__ float xw[4][NSTAT];
    if ((tid & 63) == 0) {
        int w = tid >> 6;
#pragma unroll
        for (int i = 0; i < NSTAT; i++) xw[w][i] = acc[i];
    }
    __syncthreads();
    if (tid < NSTAT)
        pstat[((b * NSTAT + tid) << 8) + blk] =
            xw[0][tid] + xw[1][tid] + xw[2][tid] + xw[3][tid];
}

// ---- Stage 2: reduce stat partials, per-instance params, out[0] = var+bg terms ----
__global__ void finalize_kernel(const float* __restrict__ pstat, float* __restrict__ wsf,
                                float* __restrict__ out) {
    __shared__ float sums[B_][NSTAT];
    __shared__ float svar[BK_];
    __shared__ int spres[BK_];
    int t = threadIdx.x;   // 256
    if (t < B_ * NSTAT) {
        const float4* p = (const float4*)(pstat + ((size_t)t << 8));
        float4 a = {0, 0, 0, 0};
        for (int j = 0; j < SBPB_ / 4; j++) {
            float4 v = p[j];
            a.x += v.x; a.y += v.y; a.z += v.z; a.w += v.w;
        }
        sums[t / NSTAT][t % NSTAT] = (a.x + a.y) + (a.z + a.w);
    }
    __syncthreads();
    if (t < BK_) {
        int b = t >> 3, k = t & 7;
        float counts = sums[b][k * 5];
        float cnt = fmaxf(counts, 1.0f);
        float smean = sums[b][k * 5 + 3] / cnt;
        float var = sums[b][k * 5 + 4] / cnt - smean * smean;  // fwd value of ref var_k
        float* fin = wsf + FIN_OFF + t * 5;
        fin[0] = sums[b][k * 5 + 1] / cnt;            // cx
        fin[1] = sums[b][k * 5 + 2] / cnt;            // cy
        fin[2] = expf(10.0f * smean);                 // sexp (accurate: feeds every dist)
        fin[3] = counts;
        fin[4] = var;
        wsf[CNT_OFF + t] = counts;
        svar[t] = var;
        spres[t] = counts > 0.0f ? 1 : 0;
    }
    __syncthreads();
    if (t == 0) {
        float o = 0.0f;
        for (int b = 0; b < B_; b++) {
            float npres = 0.0f, varl = 0.0f;
            for (int k = 0; k < K_; k++) {
                if (spres[b * K_ + k]) { npres += 1.0f; varl += svar[b * K_ + k]; }
            }
            float objf = fmaxf(npres, 1.0f);
            wsf[OBJF_OFF + b] = objf;
            wsf[BG_OFF + b] = sums[b][40];
            o += 10.0f * varl / objf + sums[b][40] / (float)N_;
        }
        out[0] = o * (1.0f / (float)B_);   // lovasz blocks atomicAdd the rest
    }
}

// ---- Stage 3: LDS histograms, ballot-aggregated hot bin, plain-store partials ----
__global__ __launch_bounds__(256) void hist_kernel(const float* __restrict__ pred,
                                                   const int* __restrict__ inst,
                                                   const float* __restrict__ wsf,
                                                   unsigned int* __restrict__ partial,
                                                   float* __restrict__ sfgpart) {
    __shared__ unsigned int hsh[K_ * MP_];   // 257-padded rows: k-rows hit distinct banks
    __shared__ float xfg[4][K_];
    int tid = threadIdx.x;
    int lane = tid & 63;
    int b = blockIdx.x >> 8;            // HBPB_ = 256 blocks per image
    int blk = blockIdx.x & (HBPB_ - 1);
    int pix0 = blk * HCH_;

    for (int i = tid; i < K_ * MP_; i += 256) hsh[i] = 0u;

    float cx[K_], cy[K_], sxp[K_];
    bool prs[K_];
#pragma unroll
    for (int k = 0; k < K_; k++) {
        const float* fin = wsf + FIN_OFF + (b * K_ + k) * 5;
        cx[k] = fin[0]; cy[k] = fin[1]; sxp[k] = fin[2];
        prs[k] = fin[3] > 0.0f;
    }
    __syncthreads();

    const float* p0p = pred + ((long long)b * 4) * N_;
    const float* p1p = p0p + N_;
    const float* p3p = p0p + 3LL * N_;
    const int* insp = inst + (long long)b * N_;

    float sfg[K_];
#pragma unroll
    for (int k = 0; k < K_; k++) sfg[k] = 0.0f;

#pragma unroll
    for (int it = 0; it < HCH_ / (256 * 4); it++) {   // 2 float4 iterations
        int base = pix0 + (it * 256 + tid) * 4;
        float4 a0 = *(const float4*)(p0p + base);
        float4 a1 = *(const float4*)(p1p + base);
        float4 a3 = *(const float4*)(p3p + base);
        int4 in4 = *(const int4*)(insp + base);
        float v0[4] = {a0.x, a0.y, a0.z, a0.w};
        float v1[4] = {a1.x, a1.y, a1.z, a1.w};
        float v3[4] = {a3.x, a3.y, a3.z, a3.w};
        int ii[4] = {in4.x, in4.y, in4.z, in4.w};
#pragma unroll
        for (int j = 0; j < 4; j++) {
            int pix = base + j;
            float sex = ftanh_(v0[j]) + (float)(pix & (W_ - 1)) * (2.0f / 2047.0f);
            float sey = ftanh_(v1[j]) + (float)(pix >> 10) * (1.0f / 1023.0f);
            float seed = fsigmoid_(v3[j]);
            int ins = ii[j];
#pragma unroll
            for (int k = 0; k < K_; k++) {
                if (prs[k]) {
                    float dx = sex - cx[k];
                    float dy = sey - cy[k];
                    float tt = sxp[k] * (dx * dx + dy * dy);
                    bool fg = (ins == k + 1);
                    // bg & far => dist<1/256 => err*128<1 => bin 0: aggregate per wave
                    bool farr = !fg && (tt > LN256_);
                    unsigned long long m = __ballot(farr);
                    if (farr) {
                        if (lane == __builtin_ctzll(m))
                            atomicAdd(&hsh[k * MP_], (unsigned)__popcll(m));
                    } else {
                        float dist = __expf(-tt);
                        float err = fg ? (2.0f - 2.0f * dist) : (2.0f * dist);
                        int bin = (int)fminf(fmaxf(err * (float)(M_ / 2), 0.0f), (float)(M_ - 1));
                        atomicAdd(&hsh[k * MP_ + bin], fg ? 0x10001u : 1u);
                        float d = seed - dist;
                        sfg[k] += fg ? d * d : 0.0f;
                    }
                }
            }
        }
    }
    __syncthreads();

    unsigned int* gp = partial + (size_t)blockIdx.x * KM_;
    for (int i = tid; i < KM_; i += 256)
        gp[i] = hsh[(i >> 8) * MP_ + (i & (M_ - 1))];

    // seed_fg: wave shfl reduce -> cross-wave LDS -> plain store
#pragma unroll
    for (int k = 0; k < K_; k++) {
        float v = sfg[k];
#pragma unroll
        for (int off = 32; off; off >>= 1) v += __shfl_down(v, off, 64);
        sfg[k] = v;
    }
    if ((tid & 63) == 0) {
        int w = tid >> 6;
#pragma unroll
        for (int k = 0; k < K_; k++) xfg[w][k] = sfg[k];
    }
    __syncthreads();
    if (tid < K_)
        sfgpart[(size_t)(b * K_ + tid) * HBPB_ + blk] =
            xfg[0][tid] + xfg[1][tid] + xfg[2][tid] + xfg[3][tid];
}

// ---- Stage 4: first-level partial reduction (256 blocks, wide memory parallelism) ----
__global__ __launch_bounds__(256) void reduce_kernel(const unsigned int* __restrict__ partial,
                                                     uint2* __restrict__ red) {
    int bk = blockIdx.x >> 3;           // (b,k)
    int s  = blockIdx.x & (SLICES_ - 1);
    int b = bk >> 3, k = bk & 7;
    int tid = threadIdx.x;              // bin
    constexpr int PER = HBPB_ / SLICES_;   // 32 hist-blocks per slice

    const unsigned int* p = partial + (size_t)(b * HBPB_ + s * PER) * KM_ + k * M_ + tid;
    unsigned int n = 0, f = 0;
#pragma unroll 8
    for (int j = 0; j < PER; j++) {
        unsigned int v = p[(size_t)j * KM_];
        n += v & 0xffffu;
        f += v >> 16;
    }
    red[(size_t)(bk * SLICES_ + s) * M_ + tid] = make_uint2(n, f);
}

// ---- Stage 5: Lovasz suffix scan + seed_fg reduce + atomicAdd into out ----
// loss = binw*[0.5*J_0 + sum_{j>=1} J_j], J_j = 1-(p-F_j)/(p+R_j-F_j),
// R,F inclusive suffix sums.
__global__ __launch_bounds__(256) void lovasz_kernel(const uint2* __restrict__ red,
                                                     const float* __restrict__ sfgpart,
                                                     const float* __restrict__ wsf,
                                                     float* __restrict__ out) {
    int bk = blockIdx.x;
    int b = bk >> 3;
    int tid = threadIdx.x;              // bin

    unsigned int n = 0, f = 0;
#pragma unroll
    for (int s = 0; s < SLICES_; s++) {
        uint2 v = red[(size_t)(bk * SLICES_ + s) * M_ + tid];
        n += v.x; f += v.y;
    }

    __shared__ unsigned int sn[256], sf[256];
    __shared__ float sacc[256];
    __shared__ float xs[4];
    sn[tid] = n; sf[tid] = f;
    __syncthreads();
    // Hillis-Steele inclusive suffix scan (8 steps)
#pragma unroll
    for (int s = 1; s < 256; s <<= 1) {
        unsigned an = sn[tid], af = sf[tid];
        unsigned bn = 0, bf = 0;
        if (tid + s < 256) { bn = sn[tid + s]; bf = sf[tid + s]; }
        __syncthreads();
        sn[tid] = an + bn; sf[tid] = af + bf;
        __syncthreads();
    }

    float pcnt = wsf[CNT_OFF + bk];
    float pp = fmaxf(pcnt, 1.0f);
    unsigned int R = sn[tid], F = sf[tid];
    float J = (R == 0) ? 0.0f : (1.0f - (pp - (float)F) / (pp + (float)(R - F)));
    sacc[tid] = (tid == 0 ? 0.5f : 1.0f) * J;
    __syncthreads();
    for (int s = 128; s > 0; s >>= 1) {
        if (tid < s) sacc[tid] += sacc[tid + s];
        __syncthreads();
    }

    // seed_fg total for this (b,k): 256 partials, one per thread
    float sv = sfgpart[(size_t)bk * HBPB_ + tid];
#pragma unroll
    for (int off = 32; off; off >>= 1) sv += __shfl_down(sv, off, 64);
    if ((tid & 63) == 0) xs[tid >> 6] = sv;
    __syncthreads();

    if (tid == 0 && pcnt > 0.0f) {
        float lov = sacc[0] * (2.0f / (float)M_);
        float sfgt = (xs[0] + xs[1]) + (xs[2] + xs[3]);
        float objf = wsf[OBJF_OFF + b];
        atomicAdd(out, (lov / objf + sfgt / (float)N_) * (1.0f / (float)B_));
    }
}

extern "C" void kernel_launch(void* const* d_in, const int* in_sizes, int n_in,
                              void* d_out, int out_size, void* d_ws, size_t ws_size,
                              hipStream_t stream) {
    const float* pred = (const float*)d_in[0];
    const int* inst = (const int*)d_in[1];
    const int* lab = (const int*)d_in[2];
    float* out = (float*)d_out;

    unsigned int* partial = (unsigned int*)d_ws;
    float* sfgpart = (float*)((char*)d_ws + SFG_OFF_B);
    uint2* red = (uint2*)((char*)d_ws + RED_OFF_B);
    float* pstat = (float*)((char*)d_ws + PSTAT_OFF_B);
    float* wsf = (float*)((char*)d_ws + WSF_OFF_B);

    // no memset: finalize initializes out[0]; all ws regions fully overwritten
    stats_kernel<<<SB_, 256, 0, stream>>>(pred, inst, lab, pstat);
    finalize_kernel<<<1, 256, 0, stream>>>(pstat, wsf, out);
    hist_kernel<<<HB_, 256, 0, stream>>>(pred, inst, wsf, partial, sfgpart);
    reduce_kernel<<<BK_ * SLICES_, 256, 0, stream>>>(partial, red);
    lovasz_kernel<<<BK_, 256, 0, stream>>>(red, sfgpart, wsf, out);
}